// Round 5
// baseline (650.516 us; speedup 1.0000x reference)
//
#include <hip/hip_runtime.h>
#include <hip/hip_bf16.h>
#include <math.h>

typedef short bf16x8 __attribute__((ext_vector_type(8)));
typedef float f32x4 __attribute__((ext_vector_type(4)));
typedef unsigned short u16;
typedef unsigned long long u64;

#define N_TOK  4096
#define D_IN   512
#define D_ATTN 64
#define NB2    2048
#define CAPW   128
#define TOPP   0.9f
#define LN_EPS 1e-5f
#define AMAXV  (N_TOK - 1)

__device__ __forceinline__ u16 f2bf(float f) {
  unsigned int u = __float_as_uint(f);
  return (u16)((u + 0x7FFFu + ((u >> 16) & 1u)) >> 16);
}

__device__ __forceinline__ void gload16(const u16* g, u16* l) {
  __builtin_amdgcn_global_load_lds(
      (const __attribute__((address_space(1))) unsigned int*)g,
      (__attribute__((address_space(3))) unsigned int*)l, 16, 0, 0);
}

// ---------------------------------------------------------------------------
// gemm128 (unchanged): C = sum_seg rowmap(A_s) @ B_s^T.
// ---------------------------------------------------------------------------
template<int EPI, int NSEG, int KSEG>
__global__ __launch_bounds__(256)
void gemm128(const u16* __restrict__ A0, int lda0, int sh0, const u16* __restrict__ B0, int ldb0,
             const u16* __restrict__ A1, int lda1, int sh1, const u16* __restrict__ B1, int ldb1,
             const u16* __restrict__ A2, int lda2, int sh2, const u16* __restrict__ B2, int ldb2,
             float* __restrict__ Cf, u16* __restrict__ Cb, u16* __restrict__ CbT,
             int ldc, int ldct)
{
  __shared__ u16 sA[2][128 * 64];
  __shared__ u16 sB[2][64 * 64];

  const int tid  = threadIdx.x;
  const int wave = tid >> 6;
  const int lane = tid & 63;
  const int l15  = lane & 15;
  const int l4   = lane >> 4;
  const int brow = blockIdx.y << 7;
  const int bcol = blockIdx.x << 6;
  const int wr64 = (wave >> 1) << 6;
  const int wc32 = (wave & 1) << 5;

  constexpr int IPSEG = KSEG >> 6;
  constexpr int TOTAL = NSEG * IPSEG;

  auto stage = [&](int buf, int it) {
    int seg = (NSEG == 1) ? 0 : (it / IPSEG);
    int kk  = (NSEG == 1) ? (it << 6) : ((it % IPSEG) << 6);
    const u16 *Ab, *Bb; int la, lb, sh;
    if (seg == 0)      { Ab = A0; la = lda0; sh = sh0; Bb = B0; lb = ldb0; }
    else if (seg == 1) { Ab = A1; la = lda1; sh = sh1; Bb = B1; lb = ldb1; }
    else               { Ab = A2; la = lda2; sh = sh2; Bb = B2; lb = ldb2; }
#pragma unroll
    for (int q = 0; q < 4; ++q) {
      int idx = q * 256 + tid;
      int row = idx >> 3;
      int chunk = (idx & 7) ^ (row & 7);
      int r = brow + row + sh;
      r = (r < 0) ? 0 : ((r > AMAXV) ? AMAXV : r);
      gload16(Ab + (size_t)r * la + kk + chunk * 8, &sA[buf][idx * 8]);
    }
#pragma unroll
    for (int q = 0; q < 2; ++q) {
      int idx = q * 256 + tid;
      int row = idx >> 3;
      int chunk = (idx & 7) ^ (row & 7);
      gload16(Bb + (size_t)(bcol + row) * lb + kk + chunk * 8, &sB[buf][idx * 8]);
    }
  };

  f32x4 acc[4][2];
#pragma unroll
  for (int m = 0; m < 4; ++m)
#pragma unroll
    for (int n = 0; n < 2; ++n) {
      acc[m][n][0] = 0.f; acc[m][n][1] = 0.f; acc[m][n][2] = 0.f; acc[m][n][3] = 0.f;
    }

  stage(0, 0);
  asm volatile("s_waitcnt vmcnt(0)" ::: "memory");
  __builtin_amdgcn_s_barrier();

  for (int i = 0; i < TOTAL; ++i) {
    const int c = i & 1;
    if (i + 1 < TOTAL) stage(c ^ 1, i + 1);
#pragma unroll
    for (int ks = 0; ks < 2; ++ks) {
      bf16x8 af[4], bfr[2];
#pragma unroll
      for (int m = 0; m < 4; ++m) {
        int ar = wr64 + m * 16 + l15;
        af[m] = *(const bf16x8*)&sA[c][ar * 64 + (((ks << 2) + l4) ^ (ar & 7)) * 8];
      }
#pragma unroll
      for (int n = 0; n < 2; ++n) {
        int br = wc32 + n * 16 + l15;
        bfr[n] = *(const bf16x8*)&sB[c][br * 64 + (((ks << 2) + l4) ^ (br & 7)) * 8];
      }
#pragma unroll
      for (int m = 0; m < 4; ++m)
#pragma unroll
        for (int n = 0; n < 2; ++n)
          acc[m][n] = __builtin_amdgcn_mfma_f32_16x16x32_bf16(af[m], bfr[n], acc[m][n], 0, 0, 0);
    }
    asm volatile("s_waitcnt vmcnt(0)" ::: "memory");
    __builtin_amdgcn_s_barrier();
  }

#pragma unroll
  for (int m = 0; m < 4; ++m)
#pragma unroll
    for (int n = 0; n < 2; ++n)
#pragma unroll
      for (int r = 0; r < 4; ++r) {
        const int row = brow + wr64 + m * 16 + l4 * 4 + r;
        const int col = bcol + wc32 + n * 16 + l15;
        const float v = acc[m][n][r];
        if (EPI == 0) Cf[(size_t)row * ldc + col] = v;
        if (EPI == 1) Cb[(size_t)row * ldc + col] = f2bf(tanhf(v));
        if (EPI == 2) Cb[(size_t)row * ldc + col] = f2bf(v);
        if (EPI == 3) Cf[(size_t)row * ldc + col] += v;
        if (EPI == 4) {
          u16 hv = f2bf(v);
          Cb [(size_t)row * ldc  + col] = hv;
          CbT[(size_t)col * ldct + row] = hv;
        }
      }
}

// ---------------------------------------------------------------------------
// Wave-synchronous nucleus with bounded multi-level bucket narrowing.
// One row per wave; zero block barriers. Lane l owns columns [64l, 64l+64).
// Level loop: histogram over candidate set -> crossing bucket s -> keep
// buckets>s, narrow cand to bucket s, range /= 2048. Ends via small exact
// refine (<=CAPW), closed-form tie rule (all-equal), or level cap.
// Reads f32 scores row from S; writes bf16 A row to A (idempotent).
// ---------------------------------------------------------------------------
__global__ __launch_bounds__(256)
void nucleus_wave(const float* __restrict__ S, u16* __restrict__ A, int apitch)
{
  const int wid = threadIdx.x >> 6;
  const int l   = threadIdx.x & 63;
  const int row = (blockIdx.x << 2) + wid;
  const float* srow = S + (size_t)row * N_TOK;
  u16* arow = A + (size_t)row * apitch;

  __shared__ float hist[4][NB2];            // 32 KB
  __shared__ float ge[4][CAPW];             // 2 KB
  __shared__ int   gcol[4][CAPW];           // 2 KB
  __shared__ unsigned char kf[4][CAPW];     // .5 KB
  __shared__ int   cnts[4];

  float* H = hist[wid];

  // ---- load row (lane-contiguous 64 cols) + wave max/min/sum
  float evf[64];
  float lmax = -3.402823466e38f, lmin = 3.402823466e38f;
#pragma unroll
  for (int q = 0; q < 16; ++q) {
    float4 v = ((const float4*)(srow + (l << 6)))[q];
    evf[4*q+0] = v.x; evf[4*q+1] = v.y; evf[4*q+2] = v.z; evf[4*q+3] = v.w;
    lmax = fmaxf(lmax, fmaxf(fmaxf(v.x, v.y), fmaxf(v.z, v.w)));
    lmin = fminf(lmin, fminf(fminf(v.x, v.y), fminf(v.z, v.w)));
  }
#pragma unroll
  for (int o = 32; o; o >>= 1) {
    lmax = fmaxf(lmax, __shfl_xor(lmax, o));
    lmin = fminf(lmin, __shfl_xor(lmin, o));
  }
  const float smax = lmax;

  // ---- exp in regs + total E
  float lE = 0.f;
#pragma unroll
  for (int qc = 0; qc < 64; ++qc) {
    float e = __expf(evf[qc] - smax);
    evf[qc] = e;
    lE += e;
  }
#pragma unroll
  for (int o = 32; o; o >>= 1) lE += __shfl_xor(lE, o);
  const float E = lE;
  const float T = TOPP * E;

  u64 keep = 0, cand = ~0ULL;
  float Agt = 0.f;
  float lo = __expf(lmin - smax);
  float width = fmaxf(1.0f - lo, 1e-30f);
  float den = E;

  for (int lev = 0; lev < 12; ++lev) {
    // candidate count + min/max value
    int myCnt = __popcll(cand);
    int tot = myCnt;
#pragma unroll
    for (int o = 32; o; o >>= 1) tot += __shfl_xor(tot, o);
    if (tot == 0) { den = Agt; break; }

    float cmin = 3.402823466e38f, cmax = -3.402823466e38f;
#pragma unroll
    for (int qc = 0; qc < 64; ++qc)
      if ((cand >> qc) & 1) { cmin = fminf(cmin, evf[qc]); cmax = fmaxf(cmax, evf[qc]); }
#pragma unroll
    for (int o = 32; o; o >>= 1) {
      cmin = fminf(cmin, __shfl_xor(cmin, o));
      cmax = fmaxf(cmax, __shfl_xor(cmax, o));
    }

    if (cmin == cmax || lev == 11) {
      // ---- closed-form tie rule: all candidates share value v
      float v = cmax;
      int r = (int)ceilf((T - Agt) / v);
      r = (r < 0) ? 0 : ((r > tot) ? tot : r);
      int sc = myCnt;
#pragma unroll
      for (int o = 1; o < 64; o <<= 1) { int t = __shfl_up(sc, o); if (l >= o) sc += t; }
      int run = sc - myCnt;               // candidates in lanes < l
#pragma unroll
      for (int qc = 0; qc < 64; ++qc) {
        if ((cand >> qc) & 1) {
          if (run < r) keep |= 1ULL << qc;
          ++run;
        }
      }
      den = Agt + (float)r * v;
      break;
    }

    if (tot <= CAPW) {
      // ---- small exact tie-aware refine via per-wave LDS list
      if (l == 0) cnts[wid] = 0;
#pragma unroll
      for (int qc = 0; qc < 64; ++qc) {
        if ((cand >> qc) & 1) {
          int i = atomicAdd(&cnts[wid], 1);
          ge[wid][i] = evf[qc];
          gcol[wid][i] = (l << 6) | qc;
        }
      }
      int cnt = cnts[wid];
      float keptb = 0.f;
      for (int i = l; i < cnt; i += 64) {
        float ei = ge[wid][i]; int ci = gcol[wid][i];
        float m = Agt;
        for (int t = 0; t < cnt; ++t) {
          float el = ge[wid][t];
          if (el > ei || (el == ei && gcol[wid][t] < ci)) m += el;
        }
        unsigned char kp = (m < T) ? 1 : 0;
        kf[wid][i] = kp;
        if (kp) keptb += ei;
      }
#pragma unroll
      for (int o = 32; o; o >>= 1) keptb += __shfl_xor(keptb, o);
      for (int t = 0; t < cnt; ++t) {
        int ct = gcol[wid][t];
        if ((ct >> 6) == l && kf[wid][t]) keep |= 1ULL << (ct & 63);
      }
      den = Agt + keptb;
      break;
    }

    // ---- narrowing level: histogram candidates into 2048 buckets over [lo, lo+width)
    const float scale = (float)NB2 / width;
    {
      float4 z4; z4.x = 0.f; z4.y = 0.f; z4.z = 0.f; z4.w = 0.f;
#pragma unroll
      for (int pc = 0; pc < 8; ++pc)
        ((float4*)(H + (l << 5)))[(pc + l) & 7] = z4;     // zero own 32 (rotated)
    }
#pragma unroll
    for (int qc = 0; qc < 64; ++qc) {
      if ((cand >> qc) & 1) {
        float e = evf[qc];
        int b = (int)((e - lo) * scale);
        b = (b < 0) ? 0 : ((b > NB2 - 1) ? NB2 - 1 : b);
        int ol = b >> 5, jc = (b >> 2) & 7;
        atomicAdd(&H[(ol << 5) + (((jc + ol) & 7) << 2) + (b & 3)], e);
      }
    }
    // read own 32 buckets (rotated, conflict-free), suffix scan across lanes
    float4 h4[8];
#pragma unroll
    for (int jc = 0; jc < 8; ++jc)
      h4[jc] = ((const float4*)(H + (l << 5)))[(jc + l) & 7];
    float sl = 0.f;
#pragma unroll
    for (int jc = 0; jc < 8; ++jc)
      sl += (h4[jc].x + h4[jc].y) + (h4[jc].z + h4[jc].w);
    float v = sl;
#pragma unroll
    for (int o = 1; o < 64; o <<= 1) {
      float t = __shfl_down(v, o);
      if (l + o < 64) v += t;
    }
    const float above = v - sl;          // candidate mass in buckets above my chunk
    // walk own 32 buckets descending, find crossing (absolute mass incl Agt)
    float Arun = Agt + above;
    int   lb = -1;
    float Ab = 0.f;
#pragma unroll
    for (int j = 31; j >= 0; --j) {
      float bm;
      switch (j & 3) {
        case 0: bm = h4[j >> 2].x; break;
        case 1: bm = h4[j >> 2].y; break;
        case 2: bm = h4[j >> 2].z; break;
        default: bm = h4[j >> 2].w; break;
      }
      if (Arun < T && Arun + bm >= T) { lb = j; Ab = Arun; }
      Arun += bm;
    }
    int bst_l = (lb >= 0) ? ((l << 5) | lb) : -1;
    int s = bst_l;
#pragma unroll
    for (int o = 32; o; o >>= 1) s = max(s, __shfl_xor(s, o));
    if (s < 0) {                          // fuzz: no crossing -> keep all cands
      float cm = 0.f;
#pragma unroll
      for (int qc = 0; qc < 64; ++qc) if ((cand >> qc) & 1) cm += evf[qc];
#pragma unroll
      for (int o = 32; o; o >>= 1) cm += __shfl_xor(cm, o);
      keep |= cand;
      den = Agt + cm;
      break;
    }
    float Ab_l = (bst_l == s) ? Ab : 0.f;
#pragma unroll
    for (int o = 32; o; o >>= 1) Ab_l += __shfl_xor(Ab_l, o);
    // update keep/cand masks, Agt, range
    u64 nkeep = 0, ncand = 0;
#pragma unroll
    for (int qc = 0; qc < 64; ++qc) {
      if ((cand >> qc) & 1) {
        float e = evf[qc];
        int b = (int)((e - lo) * scale);
        b = (b < 0) ? 0 : ((b > NB2 - 1) ? NB2 - 1 : b);
        if (b > s) nkeep |= 1ULL << qc;
        else if (b == s) ncand |= 1ULL << qc;
      }
    }
    keep |= nkeep;
    cand = ncand;
    Agt = Ab_l;
    width = width * (1.0f / NB2);
    lo = lo + (float)s * width;
  }

  const float invd = 1.0f / den;

  // ---- write A row as bf16 (lane-contiguous columns)
#pragma unroll
  for (int q = 0; q < 16; ++q) {
    u16 rr[4];
#pragma unroll
    for (int c = 0; c < 4; ++c) {
      int qc = 4 * q + c;
      float val = ((keep >> qc) & 1) ? evf[qc] * invd : 0.f;
      rr[c] = f2bf(val);
    }
    ((ushort4*)(arow + (l << 6)))[q] = make_ushort4(rr[0], rr[1], rr[2], rr[3]);
  }
}

// ---------------------------------------------------------------------------
__global__ void cvt_bf4(const float* __restrict__ src, u16* __restrict__ d1,
                        u16* __restrict__ d2, int n4)
{
  int i = blockIdx.x * 256 + threadIdx.x;
  if (i < n4) {
    float4 v = ((const float4*)src)[i];
    ushort4 o;
    o.x = f2bf(v.x); o.y = f2bf(v.y); o.z = f2bf(v.z); o.w = f2bf(v.w);
    ((ushort4*)d1)[i] = o;
    if (d2) ((ushort4*)d2)[i] = o;
  }
}

__global__ __launch_bounds__(256)
void tpose_bf(const float* __restrict__ X, u16* __restrict__ XT)
{
  __shared__ u16 tile[32][33];
  const int bc = blockIdx.x * 32;
  const int br = blockIdx.y * 32;
  const int tx = threadIdx.x & 31, ty = threadIdx.x >> 5;
#pragma unroll
  for (int i = 0; i < 32; i += 8)
    tile[ty + i][tx] = f2bf(X[(size_t)(br + ty + i) * D_IN + bc + tx]);
  __syncthreads();
#pragma unroll
  for (int i = 0; i < 32; i += 8)
    XT[(size_t)(bc + ty + i) * N_TOK + br + tx] = tile[tx][ty + i];
}

__global__ __launch_bounds__(256)
void ln_kernel(const float* __restrict__ X, float* Z,
               const float* __restrict__ gamma, const float* __restrict__ beta)
{
  const int row = blockIdx.x, tid = threadIdx.x;
  const size_t base = (size_t)row * D_IN;
  __shared__ float red[4];
  __shared__ float s_mu, s_var;
  float y0 = X[base + tid] + Z[base + tid];
  float y1 = X[base + tid + 256] + Z[base + tid + 256];
  float s = y0 + y1;
  for (int o = 32; o; o >>= 1) s += __shfl_xor(s, o);
  if ((tid & 63) == 0) red[tid >> 6] = s;
  __syncthreads();
  if (tid == 0) s_mu = (red[0] + red[1] + red[2] + red[3]) * (1.f / D_IN);
  __syncthreads();
  const float mu = s_mu;
  float d0 = y0 - mu, d1 = y1 - mu;
  float v = d0 * d0 + d1 * d1;
  for (int o = 32; o; o >>= 1) v += __shfl_xor(v, o);
  if ((tid & 63) == 0) red[tid >> 6] = v;
  __syncthreads();
  if (tid == 0) s_var = (red[0] + red[1] + red[2] + red[3]) * (1.f / D_IN);
  __syncthreads();
  const float rs = rsqrtf(s_var + LN_EPS);
  Z[base + tid]       = d0 * rs * gamma[tid]       + beta[tid];
  Z[base + tid + 256] = d1 * rs * gamma[tid + 256] + beta[tid + 256];
}

// ---------------------------------------------------------------------------
extern "C" void kernel_launch(void* const* d_in, const int* in_sizes, int n_in,
                              void* d_out, int out_size, void* d_ws, size_t ws_size,
                              hipStream_t stream)
{
  const float* X     = (const float*)d_in[0];
  const float* W1    = (const float*)d_in[1];
  const float* W2    = (const float*)d_in[2];
  const float* W3    = (const float*)d_in[3];
  const float* U1    = (const float*)d_in[4];
  const float* U2    = (const float*)d_in[5];
  const float* U3    = (const float*)d_in[6];
  const float* gamma = (const float*)d_in[7];
  const float* beta  = (const float*)d_in[8];

  char* w = (char*)d_ws;
  float* S    = (float*)w;            w += (size_t)N_TOK * N_TOK * 4;   // 64 MB
  u16* Xbf    = (u16*)w;              w += (size_t)N_TOK * D_IN * 2;
  u16* Xa0    = (u16*)w;              w += (size_t)N_TOK * D_IN * 2;
  u16* Xa1    = (u16*)w;              w += (size_t)N_TOK * D_IN * 2;
  u16* XaT0   = (u16*)w;              w += (size_t)D_IN * N_TOK * 2;
  u16* XaT1   = (u16*)w;              w += (size_t)D_IN * N_TOK * 2;
  u16* hb     = (u16*)w;              w += (size_t)N_TOK * D_ATTN * 2;
  u16* qb     = (u16*)w;              w += (size_t)N_TOK * D_ATTN * 2;
  u16* kb     = (u16*)w;              w += (size_t)N_TOK * D_ATTN * 2;
  u16* W1b    = (u16*)w;              w += (size_t)D_ATTN * D_IN * 2;
  u16* W2b    = (u16*)w;              w += (size_t)D_ATTN * D_ATTN * 2;
  u16* W3b    = (u16*)w;              w += (size_t)D_ATTN * D_IN * 2;
  u16* U1b    = (u16*)w;              w += (size_t)2 * D_IN * D_IN * 2;
  u16* U2b    = (u16*)w;              w += (size_t)2 * D_IN * D_IN * 2;
  u16* U3b    = (u16*)w;              w += (size_t)2 * D_IN * D_IN * 2;

  // A gets its own buffer if workspace allows (idempotent nucleus); else
  // fall back to in-place over S (first half of each 16KB row).
  size_t used = (size_t)(w - (char*)d_ws);
  u16* Abuf;
  int  apitch;
  if (ws_size >= used + (size_t)N_TOK * N_TOK * 2) {
    Abuf = (u16*)w;
    apitch = N_TOK;
  } else {
    Abuf = (u16*)S;
    apitch = 2 * N_TOK;
  }

  float* Z = (float*)d_out;

  hipMemsetAsync(d_out, 0, (size_t)N_TOK * D_IN * 4, stream);

  const int nXD4 = N_TOK * D_IN / 4;
  cvt_bf4<<<(nXD4 + 255) / 256, 256, 0, stream>>>(X, Xbf, Xa0, nXD4);
  cvt_bf4<<<(D_ATTN * D_IN / 4 + 255) / 256, 256, 0, stream>>>(W1, W1b, nullptr, D_ATTN * D_IN / 4);
  cvt_bf4<<<(D_ATTN * D_ATTN / 4 + 255) / 256, 256, 0, stream>>>(W2, W2b, nullptr, D_ATTN * D_ATTN / 4);
  cvt_bf4<<<(D_ATTN * D_IN / 4 + 255) / 256, 256, 0, stream>>>(W3, W3b, nullptr, D_ATTN * D_IN / 4);
  const int nU4 = 2 * D_IN * D_IN / 4;
  cvt_bf4<<<(nU4 + 255) / 256, 256, 0, stream>>>(U1, U1b, nullptr, nU4);
  cvt_bf4<<<(nU4 + 255) / 256, 256, 0, stream>>>(U2, U2b, nullptr, nU4);
  cvt_bf4<<<(nU4 + 255) / 256, 256, 0, stream>>>(U3, U3b, nullptr, nU4);
  tpose_bf<<<dim3(D_IN / 32, N_TOK / 32), 256, 0, stream>>>(X, XaT0);

  u16* XaC[2]  = {Xa0, Xa1};
  u16* XaTC[2] = {XaT0, XaT1};

  for (int n = 0; n < 2; ++n) {
    const int cur = n & 1, nxt = cur ^ 1;
    const size_t uoff = (size_t)n * D_IN * D_IN;
    // h = tanh(Xa @ W1^T)  [4096,64]
    gemm128<1, 1, D_IN><<<dim3(1, 32), 256, 0, stream>>>(
        XaC[cur], D_IN, 0, W1b, D_IN,
        nullptr, 0, 0, nullptr, 0, nullptr, 0, 0, nullptr, 0,
        nullptr, hb, nullptr, D_ATTN, 0);
    // k = Xa @ W3^T
    gemm128<2, 1, D_IN><<<dim3(1, 32), 256, 0, stream>>>(
        XaC[cur], D_IN, 0, W3b, D_IN,
        nullptr, 0, 0, nullptr, 0, nullptr, 0, 0, nullptr, 0,
        nullptr, kb, nullptr, D_ATTN, 0);
    // q = h @ W2^T
    gemm128<2, 1, D_ATTN><<<dim3(1, 32), 256, 0, stream>>>(
        hb, D_ATTN, 0, W2b, D_ATTN,
        nullptr, 0, 0, nullptr, 0, nullptr, 0, 0, nullptr, 0,
        nullptr, qb, nullptr, D_ATTN, 0);
    // S = q @ k^T
    gemm128<0, 1, D_ATTN><<<dim3(64, 32), 256, 0, stream>>>(
        qb, D_ATTN, 0, kb, D_ATTN,
        nullptr, 0, 0, nullptr, 0, nullptr, 0, 0, nullptr, 0,
        S, nullptr, nullptr, N_TOK, 0);
    // softmax + top-p -> A (bf16; one row per wave; idempotent)
    nucleus_wave<<<N_TOK / 4, 256, 0, stream>>>(S, Abuf, apitch);
    // Xa_new = A @ Xa : B = XaT cur; dual-write Xa_new, XaT_new
    gemm128<4, 1, N_TOK><<<dim3(8, 32), 256, 0, stream>>>(
        Abuf, apitch, 0, XaTC[cur], N_TOK,
        nullptr, 0, 0, nullptr, 0, nullptr, 0, 0, nullptr, 0,
        nullptr, XaC[nxt], XaTC[nxt], D_IN, N_TOK);
    // Z += Xf@U1^T + Xb@U2^T + Xa_new@U3^T   (fused 3-segment)
    gemm128<3, 3, D_IN><<<dim3(8, 32), 256, 0, stream>>>(
        Xbf, D_IN, -(n + 1), U1b + uoff, D_IN,
        Xbf, D_IN,  (n + 1), U2b + uoff, D_IN,
        XaC[nxt], D_IN, 0,   U3b + uoff, D_IN,
        Z, nullptr, nullptr, D_IN, 0);
  }

  // y = X + Z ; LayerNorm (in place over Z = d_out)
  ln_kernel<<<N_TOK, 256, 0, stream>>>(X, Z, gamma, beta);
}

// Round 6
// 571.171 us; speedup vs baseline: 1.1389x; 1.1389x over previous
//
#include <hip/hip_runtime.h>
#include <hip/hip_bf16.h>
#include <math.h>

typedef short bf16x8 __attribute__((ext_vector_type(8)));
typedef float f32x4 __attribute__((ext_vector_type(4)));
typedef unsigned short u16;

#define N_TOK  4096
#define D_IN   512
#define D_ATTN 64
#define NB2    2048
#define CAPW   128
#define TOPP   0.9f
#define LN_EPS 1e-5f
#define AMAXV  (N_TOK - 1)
#define FLTMAX 3.402823466e38f

__device__ __forceinline__ u16 f2bf(float f) {
  unsigned int u = __float_as_uint(f);
  return (u16)((u + 0x7FFFu + ((u >> 16) & 1u)) >> 16);
}

__device__ __forceinline__ void gload16(const u16* g, u16* l) {
  __builtin_amdgcn_global_load_lds(
      (const __attribute__((address_space(1))) unsigned int*)g,
      (__attribute__((address_space(3))) unsigned int*)l, 16, 0, 0);
}

// ---------------------------------------------------------------------------
// gemm128: C = sum_seg rowmap(A_s) @ B_s^T.  BM=128, BN=64, BK=64.
// EPI: 0 f32; 1 tanh->bf16; 2 bf16; 3 f32 +=; 4 bf16 dual (C,C^T);
//      5 split: col<64 -> tanh->Cb, col>=64 -> CbT (h+k fusion)
// ---------------------------------------------------------------------------
template<int EPI, int NSEG, int KSEG>
__global__ __launch_bounds__(256)
void gemm128(const u16* __restrict__ A0, int lda0, int sh0, const u16* __restrict__ B0, int ldb0,
             const u16* __restrict__ A1, int lda1, int sh1, const u16* __restrict__ B1, int ldb1,
             const u16* __restrict__ A2, int lda2, int sh2, const u16* __restrict__ B2, int ldb2,
             float* __restrict__ Cf, u16* __restrict__ Cb, u16* __restrict__ CbT,
             int ldc, int ldct)
{
  __shared__ u16 sA[2][128 * 64];
  __shared__ u16 sB[2][64 * 64];

  const int tid  = threadIdx.x;
  const int wave = tid >> 6;
  const int lane = tid & 63;
  const int l15  = lane & 15;
  const int l4   = lane >> 4;
  const int brow = blockIdx.y << 7;
  const int bcol = blockIdx.x << 6;
  const int wr64 = (wave >> 1) << 6;
  const int wc32 = (wave & 1) << 5;

  constexpr int IPSEG = KSEG >> 6;
  constexpr int TOTAL = NSEG * IPSEG;

  auto stage = [&](int buf, int it) {
    int seg = (NSEG == 1) ? 0 : (it / IPSEG);
    int kk  = (NSEG == 1) ? (it << 6) : ((it % IPSEG) << 6);
    const u16 *Ab, *Bb; int la, lb, sh;
    if (seg == 0)      { Ab = A0; la = lda0; sh = sh0; Bb = B0; lb = ldb0; }
    else if (seg == 1) { Ab = A1; la = lda1; sh = sh1; Bb = B1; lb = ldb1; }
    else               { Ab = A2; la = lda2; sh = sh2; Bb = B2; lb = ldb2; }
#pragma unroll
    for (int q = 0; q < 4; ++q) {
      int idx = q * 256 + tid;
      int row = idx >> 3;
      int chunk = (idx & 7) ^ (row & 7);
      int r = brow + row + sh;
      r = (r < 0) ? 0 : ((r > AMAXV) ? AMAXV : r);
      gload16(Ab + (size_t)r * la + kk + chunk * 8, &sA[buf][idx * 8]);
    }
#pragma unroll
    for (int q = 0; q < 2; ++q) {
      int idx = q * 256 + tid;
      int row = idx >> 3;
      int chunk = (idx & 7) ^ (row & 7);
      gload16(Bb + (size_t)(bcol + row) * lb + kk + chunk * 8, &sB[buf][idx * 8]);
    }
  };

  f32x4 acc[4][2];
#pragma unroll
  for (int m = 0; m < 4; ++m)
#pragma unroll
    for (int n = 0; n < 2; ++n) {
      acc[m][n][0] = 0.f; acc[m][n][1] = 0.f; acc[m][n][2] = 0.f; acc[m][n][3] = 0.f;
    }

  stage(0, 0);
  asm volatile("s_waitcnt vmcnt(0)" ::: "memory");
  __builtin_amdgcn_s_barrier();

  for (int i = 0; i < TOTAL; ++i) {
    const int c = i & 1;
    if (i + 1 < TOTAL) stage(c ^ 1, i + 1);
#pragma unroll
    for (int ks = 0; ks < 2; ++ks) {
      bf16x8 af[4], bfr[2];
#pragma unroll
      for (int m = 0; m < 4; ++m) {
        int ar = wr64 + m * 16 + l15;
        af[m] = *(const bf16x8*)&sA[c][ar * 64 + (((ks << 2) + l4) ^ (ar & 7)) * 8];
      }
#pragma unroll
      for (int n = 0; n < 2; ++n) {
        int br = wc32 + n * 16 + l15;
        bfr[n] = *(const bf16x8*)&sB[c][br * 64 + (((ks << 2) + l4) ^ (br & 7)) * 8];
      }
#pragma unroll
      for (int m = 0; m < 4; ++m)
#pragma unroll
        for (int n = 0; n < 2; ++n)
          acc[m][n] = __builtin_amdgcn_mfma_f32_16x16x32_bf16(af[m], bfr[n], acc[m][n], 0, 0, 0);
    }
    asm volatile("s_waitcnt vmcnt(0)" ::: "memory");
    __builtin_amdgcn_s_barrier();
  }

#pragma unroll
  for (int m = 0; m < 4; ++m)
#pragma unroll
    for (int n = 0; n < 2; ++n)
#pragma unroll
      for (int r = 0; r < 4; ++r) {
        const int row = brow + wr64 + m * 16 + l4 * 4 + r;
        const int col = bcol + wc32 + n * 16 + l15;
        const float v = acc[m][n][r];
        if (EPI == 0) Cf[(size_t)row * ldc + col] = v;
        if (EPI == 1) Cb[(size_t)row * ldc + col] = f2bf(tanhf(v));
        if (EPI == 2) Cb[(size_t)row * ldc + col] = f2bf(v);
        if (EPI == 3) Cf[(size_t)row * ldc + col] += v;
        if (EPI == 4) {
          u16 hv = f2bf(v);
          Cb [(size_t)row * ldc  + col] = hv;
          CbT[(size_t)col * ldct + row] = hv;
        }
        if (EPI == 5) {
          if (col < 64) Cb [(size_t)row * 64 + col]        = f2bf(tanhf(v));
          else          CbT[(size_t)row * 64 + (col - 64)] = f2bf(v);
        }
      }
}

// ---------------------------------------------------------------------------
// Block-per-row nucleus with bounded multi-level bucket narrowing.
// 256 threads/row; thread t owns cols {1024q + 4t + j : q=0..3, j=0..3}
// (coalesced float4 loads / ushort4 stores). Level loop: shared 2048-bucket
// exp-mass histogram -> parallel scan -> crossing bucket s -> keep b>s,
// cand=b==s, range/=2048. Terminal: exact tie-aware refine (<=128), closed
// form all-equal ties, or level cap. Writes bf16 A row (idempotent).
// ---------------------------------------------------------------------------
__global__ __launch_bounds__(256)
void nucleus_block(const float* __restrict__ S, u16* __restrict__ A, int apitch)
{
  const int row = blockIdx.x, t = threadIdx.x;
  const int wv = t >> 6, ln = t & 63;
  const float* srow = S + (size_t)row * N_TOK;
  u16* arow = A + (size_t)row * apitch;

  __shared__ float hist[NB2];              // 8 KB
  __shared__ float ge[CAPW];
  __shared__ int   gcol[CAPW];
  __shared__ unsigned char kf[CAPW];
  __shared__ float rA[4], rB[4], rC[4];
  __shared__ int   riA[4];
  __shared__ int   wti[4][4];
  __shared__ float s_Ab;
  __shared__ int   s_cnt;

  // ---- load + max/min (coalesced)
  float evf[16];
  float lmax = -FLTMAX, lmin = FLTMAX;
#pragma unroll
  for (int q = 0; q < 4; ++q) {
    float4 v = ((const float4*)srow)[q * 256 + t];
    evf[4*q+0] = v.x; evf[4*q+1] = v.y; evf[4*q+2] = v.z; evf[4*q+3] = v.w;
    lmax = fmaxf(lmax, fmaxf(fmaxf(v.x, v.y), fmaxf(v.z, v.w)));
    lmin = fminf(lmin, fminf(fminf(v.x, v.y), fminf(v.z, v.w)));
  }
#pragma unroll
  for (int o = 32; o; o >>= 1) {
    lmax = fmaxf(lmax, __shfl_xor(lmax, o));
    lmin = fminf(lmin, __shfl_xor(lmin, o));
  }
  if (ln == 0) { rA[wv] = lmax; rB[wv] = lmin; }
  __syncthreads();
  const float smax = fmaxf(fmaxf(rA[0], rA[1]), fmaxf(rA[2], rA[3]));
  const float smin = fminf(fminf(rB[0], rB[1]), fminf(rB[2], rB[3]));

  // ---- exp in regs + total E
  float lE = 0.f;
#pragma unroll
  for (int j = 0; j < 16; ++j) {
    float e = __expf(evf[j] - smax);
    evf[j] = e;
    lE += e;
  }
#pragma unroll
  for (int o = 32; o; o >>= 1) lE += __shfl_xor(lE, o);
  if (ln == 0) rC[wv] = lE;
  __syncthreads();
  const float E = rC[0] + rC[1] + rC[2] + rC[3];
  const float T = TOPP * E;

  unsigned int keep = 0, cand = 0xFFFFu;
  float Agt = 0.f;
  float lo = __expf(smin - smax);
  float width = fmaxf(1.0f - lo, 1e-30f);
  float den = E;

  for (int lev = 0; lev < 12; ++lev) {
    __syncthreads();                       // protect shared scratch reuse
    // candidate count + value min/max
    int myCnt = __popc(cand);
    float cmin = FLTMAX, cmax = -FLTMAX;
#pragma unroll
    for (int j = 0; j < 16; ++j)
      if ((cand >> j) & 1) { float e = evf[j]; cmin = fminf(cmin, e); cmax = fmaxf(cmax, e); }
    int ct = myCnt;
#pragma unroll
    for (int o = 32; o; o >>= 1) {
      ct   += __shfl_xor(ct, o);
      cmin  = fminf(cmin, __shfl_xor(cmin, o));
      cmax  = fmaxf(cmax, __shfl_xor(cmax, o));
    }
    if (ln == 0) { riA[wv] = ct; rA[wv] = cmin; rB[wv] = cmax; }
    __syncthreads();
    const int tot = riA[0] + riA[1] + riA[2] + riA[3];
    cmin = fminf(fminf(rA[0], rA[1]), fminf(rA[2], rA[3]));
    cmax = fmaxf(fmaxf(rB[0], rB[1]), fmaxf(rB[2], rB[3]));

    if (tot == 0) { den = Agt; break; }

    if (cmin == cmax || lev == 11) {
      // ---- closed-form tie rule: all candidates share value v (ties kept
      // in ascending column order). Rank = col-order index among candidates.
      const float v = cmax;
      int r = (int)ceilf((T - Agt) / v);
      r = (r < 0) ? 0 : ((r > tot) ? tot : r);
      int cq[4], excl[4];
#pragma unroll
      for (int q = 0; q < 4; ++q) {
        cq[q] = __popc((cand >> (4 * q)) & 0xF);
        int sc = cq[q];
#pragma unroll
        for (int o = 1; o < 64; o <<= 1) { int u = __shfl_up(sc, o); if (ln >= o) sc += u; }
        if (ln == 63) wti[q][wv] = sc;
        excl[q] = sc - cq[q];
      }
      __syncthreads();
      int qtot[4], woff[4];
#pragma unroll
      for (int q = 0; q < 4; ++q) {
        woff[q] = (wv > 0 ? wti[q][0] : 0) + (wv > 1 ? wti[q][1] : 0) + (wv > 2 ? wti[q][2] : 0);
        qtot[q] = wti[q][0] + wti[q][1] + wti[q][2] + wti[q][3];
      }
      int qbase = 0;
#pragma unroll
      for (int q = 0; q < 4; ++q) {
        int seen = 0;
#pragma unroll
        for (int jj = 0; jj < 4; ++jj) {
          int j = 4 * q + jj;
          if ((cand >> j) & 1) {
            int rank = qbase + woff[q] + excl[q] + seen;
            if (rank < r) keep |= 1u << j;
            ++seen;
          }
        }
        qbase += qtot[q];
      }
      den = Agt + (float)r * v;
      break;
    }

    if (tot <= CAPW) {
      // ---- exact tie-aware refine: one list element per thread
      if (t == 0) s_cnt = 0;
      __syncthreads();
#pragma unroll
      for (int j = 0; j < 16; ++j) {
        if ((cand >> j) & 1) {
          int i = atomicAdd(&s_cnt, 1);
          ge[i] = evf[j];
          gcol[i] = ((j >> 2) << 10) + (t << 2) + (j & 3);
        }
      }
      __syncthreads();
      const int cnt = s_cnt;
      float lk = 0.f;
      if (t < cnt) {
        float ei = ge[t]; int ci = gcol[t];
        float m = Agt;
        for (int u = 0; u < cnt; ++u) {
          float el = ge[u];
          if (el > ei || (el == ei && gcol[u] < ci)) m += el;
        }
        unsigned char kp = (m < T) ? 1 : 0;
        kf[t] = kp;
        if (kp) lk = ei;
      }
#pragma unroll
      for (int o = 32; o; o >>= 1) lk += __shfl_xor(lk, o);
      if (ln == 0) rC[wv] = lk;
      __syncthreads();
      den = Agt + (rC[0] + rC[1] + rC[2] + rC[3]);
      for (int u = 0; u < cnt; ++u) {
        int c = gcol[u];
        if (((c >> 2) & 255) == t && kf[u])
          keep |= 1u << (((c >> 10) << 2) | (c & 3));
      }
      break;
    }

    // ---- narrowing level
    const float scale = (float)NB2 / width;
    {
      f32x4 z; z[0] = 0.f; z[1] = 0.f; z[2] = 0.f; z[3] = 0.f;
      ((f32x4*)hist)[2 * t]     = z;
      ((f32x4*)hist)[2 * t + 1] = z;
    }
    __syncthreads();
#pragma unroll
    for (int j = 0; j < 16; ++j) {
      if ((cand >> j) & 1) {
        float e = evf[j];
        int b = (int)((e - lo) * scale);
        b = (b < 0) ? 0 : ((b > NB2 - 1) ? NB2 - 1 : b);
        atomicAdd(&hist[b], e);
      }
    }
    __syncthreads();
    // thread t owns ascending buckets [8t, 8t+8)
    float hv[8];
    {
      f32x4 h0 = ((const f32x4*)hist)[2 * t];
      f32x4 h1 = ((const f32x4*)hist)[2 * t + 1];
      hv[0] = h0[0]; hv[1] = h0[1]; hv[2] = h0[2]; hv[3] = h0[3];
      hv[4] = h1[0]; hv[5] = h1[1]; hv[6] = h1[2]; hv[7] = h1[3];
    }
    float sl = ((hv[0] + hv[1]) + (hv[2] + hv[3])) + ((hv[4] + hv[5]) + (hv[6] + hv[7]));
    float pv = sl;
#pragma unroll
    for (int o = 1; o < 64; o <<= 1) { float u = __shfl_up(pv, o); if (ln >= o) pv += u; }
    if (ln == 63) rA[wv] = pv;
    __syncthreads();
    const float woff = (wv > 0 ? rA[0] : 0.f) + (wv > 1 ? rA[1] : 0.f) + (wv > 2 ? rA[2] : 0.f);
    const float CM   = rA[0] + rA[1] + rA[2] + rA[3];
    const float incl = pv + woff;          // ascending inclusive prefix
    float Arun = Agt + (CM - incl);        // mass above my top bucket
    int lb = -1; float Ab = 0.f;
#pragma unroll
    for (int j = 7; j >= 0; --j) {
      float bm = hv[j];
      if (Arun < T && Arun + bm >= T) { lb = j; Ab = Arun; }
      Arun += bm;
    }
    int bl = (lb >= 0) ? ((t << 3) | lb) : -1;
    int s = bl;
#pragma unroll
    for (int o = 32; o; o >>= 1) s = max(s, __shfl_xor(s, o));
    if (ln == 0) riA[wv] = s;
    __syncthreads();
    s = max(max(riA[0], riA[1]), max(riA[2], riA[3]));
    if (s < 0) { keep |= cand; den = Agt + CM; break; }
    if (bl == s) s_Ab = Ab;
    __syncthreads();
    const float Abnd = s_Ab;
    unsigned int nk = 0, nc = 0;
#pragma unroll
    for (int j = 0; j < 16; ++j) {
      if ((cand >> j) & 1) {
        float e = evf[j];
        int b = (int)((e - lo) * scale);
        b = (b < 0) ? 0 : ((b > NB2 - 1) ? NB2 - 1 : b);
        if (b > s) nk |= 1u << j;
        else if (b == s) nc |= 1u << j;
      }
    }
    keep |= nk;
    cand = nc;
    Agt = Abnd;
    width = fmaxf(width * (1.0f / NB2), 1e-37f);
    lo = lo + (float)s * width;
  }

  const float invd = 1.0f / den;

  // ---- write A row as bf16 (coalesced)
#pragma unroll
  for (int q = 0; q < 4; ++q) {
    u16 rr[4];
#pragma unroll
    for (int j = 0; j < 4; ++j) {
      int b = 4 * q + j;
      float val = ((keep >> b) & 1) ? evf[b] * invd : 0.f;
      rr[j] = f2bf(val);
    }
    ((ushort4*)arow)[q * 256 + t] = make_ushort4(rr[0], rr[1], rr[2], rr[3]);
  }
}

// ---------------------------------------------------------------------------
__global__ void cvt_bf4(const float* __restrict__ src, u16* __restrict__ d1,
                        u16* __restrict__ d2, int n4)
{
  int i = blockIdx.x * 256 + threadIdx.x;
  if (i < n4) {
    float4 v = ((const float4*)src)[i];
    ushort4 o;
    o.x = f2bf(v.x); o.y = f2bf(v.y); o.z = f2bf(v.z); o.w = f2bf(v.w);
    ((ushort4*)d1)[i] = o;
    if (d2) ((ushort4*)d2)[i] = o;
  }
}

__global__ __launch_bounds__(256)
void tpose_bf(const float* __restrict__ X, u16* __restrict__ XT)
{
  __shared__ u16 tile[32][33];
  const int bc = blockIdx.x * 32;
  const int br = blockIdx.y * 32;
  const int tx = threadIdx.x & 31, ty = threadIdx.x >> 5;
#pragma unroll
  for (int i = 0; i < 32; i += 8)
    tile[ty + i][tx] = f2bf(X[(size_t)(br + ty + i) * D_IN + bc + tx]);
  __syncthreads();
#pragma unroll
  for (int i = 0; i < 32; i += 8)
    XT[(size_t)(bc + ty + i) * N_TOK + br + tx] = tile[tx][ty + i];
}

__global__ __launch_bounds__(256)
void ln_kernel(const float* __restrict__ X, float* Z,
               const float* __restrict__ gamma, const float* __restrict__ beta)
{
  const int row = blockIdx.x, tid = threadIdx.x;
  const size_t base = (size_t)row * D_IN;
  __shared__ float red[4];
  __shared__ float s_mu, s_var;
  float y0 = X[base + tid] + Z[base + tid];
  float y1 = X[base + tid + 256] + Z[base + tid + 256];
  float s = y0 + y1;
  for (int o = 32; o; o >>= 1) s += __shfl_xor(s, o);
  if ((tid & 63) == 0) red[tid >> 6] = s;
  __syncthreads();
  if (tid == 0) s_mu = (red[0] + red[1] + red[2] + red[3]) * (1.f / D_IN);
  __syncthreads();
  const float mu = s_mu;
  float d0 = y0 - mu, d1 = y1 - mu;
  float v = d0 * d0 + d1 * d1;
  for (int o = 32; o; o >>= 1) v += __shfl_xor(v, o);
  if ((tid & 63) == 0) red[tid >> 6] = v;
  __syncthreads();
  if (tid == 0) s_var = (red[0] + red[1] + red[2] + red[3]) * (1.f / D_IN);
  __syncthreads();
  const float rs = rsqrtf(s_var + LN_EPS);
  Z[base + tid]       = d0 * rs * gamma[tid]       + beta[tid];
  Z[base + tid + 256] = d1 * rs * gamma[tid + 256] + beta[tid + 256];
}

// ---------------------------------------------------------------------------
extern "C" void kernel_launch(void* const* d_in, const int* in_sizes, int n_in,
                              void* d_out, int out_size, void* d_ws, size_t ws_size,
                              hipStream_t stream)
{
  const float* X     = (const float*)d_in[0];
  const float* W1    = (const float*)d_in[1];
  const float* W2    = (const float*)d_in[2];
  const float* W3    = (const float*)d_in[3];
  const float* U1    = (const float*)d_in[4];
  const float* U2    = (const float*)d_in[5];
  const float* U3    = (const float*)d_in[6];
  const float* gamma = (const float*)d_in[7];
  const float* beta  = (const float*)d_in[8];

  char* w = (char*)d_ws;
  float* S    = (float*)w;            w += (size_t)N_TOK * N_TOK * 4;   // 64 MB
  u16* Xbf    = (u16*)w;              w += (size_t)N_TOK * D_IN * 2;
  u16* Xa0    = (u16*)w;              w += (size_t)N_TOK * D_IN * 2;
  u16* Xa1    = (u16*)w;              w += (size_t)N_TOK * D_IN * 2;
  u16* XaT0   = (u16*)w;              w += (size_t)D_IN * N_TOK * 2;
  u16* XaT1   = (u16*)w;              w += (size_t)D_IN * N_TOK * 2;
  u16* hb     = (u16*)w;              w += (size_t)N_TOK * D_ATTN * 2;
  u16* qb     = (u16*)w;              w += (size_t)N_TOK * D_ATTN * 2;
  u16* kb     = (u16*)w;              w += (size_t)N_TOK * D_ATTN * 2;
  u16* W13b   = (u16*)w;              w += (size_t)2 * D_ATTN * D_IN * 2;  // [W1;W3] stacked
  u16* W2b    = (u16*)w;              w += (size_t)D_ATTN * D_ATTN * 2;
  u16* U1b    = (u16*)w;              w += (size_t)2 * D_IN * D_IN * 2;
  u16* U2b    = (u16*)w;              w += (size_t)2 * D_IN * D_IN * 2;
  u16* U3b    = (u16*)w;              w += (size_t)2 * D_IN * D_IN * 2;

  // A buffer (idempotent nucleus) if workspace allows, else in-place over S.
  size_t used = (size_t)(w - (char*)d_ws);
  u16* Abuf;
  int  apitch;
  if (ws_size >= used + (size_t)N_TOK * N_TOK * 2) {
    Abuf = (u16*)w;
    apitch = N_TOK;
  } else {
    Abuf = (u16*)S;
    apitch = 2 * N_TOK;
  }

  float* Z = (float*)d_out;

  hipMemsetAsync(d_out, 0, (size_t)N_TOK * D_IN * 4, stream);

  const int nXD4 = N_TOK * D_IN / 4;
  cvt_bf4<<<(nXD4 + 255) / 256, 256, 0, stream>>>(X, Xbf, Xa0, nXD4);
  const int nW4 = D_ATTN * D_IN / 4;
  cvt_bf4<<<(nW4 + 255) / 256, 256, 0, stream>>>(W1, W13b, nullptr, nW4);
  cvt_bf4<<<(nW4 + 255) / 256, 256, 0, stream>>>(W3, W13b + (size_t)D_ATTN * D_IN, nullptr, nW4);
  cvt_bf4<<<(D_ATTN * D_ATTN / 4 + 255) / 256, 256, 0, stream>>>(W2, W2b, nullptr, D_ATTN * D_ATTN / 4);
  const int nU4 = 2 * D_IN * D_IN / 4;
  cvt_bf4<<<(nU4 + 255) / 256, 256, 0, stream>>>(U1, U1b, nullptr, nU4);
  cvt_bf4<<<(nU4 + 255) / 256, 256, 0, stream>>>(U2, U2b, nullptr, nU4);
  cvt_bf4<<<(nU4 + 255) / 256, 256, 0, stream>>>(U3, U3b, nullptr, nU4);
  tpose_bf<<<dim3(D_IN / 32, N_TOK / 32), 256, 0, stream>>>(X, XaT0);

  u16* XaC[2]  = {Xa0, Xa1};
  u16* XaTC[2] = {XaT0, XaT1};

  for (int n = 0; n < 2; ++n) {
    const int cur = n & 1, nxt = cur ^ 1;
    const size_t uoff = (size_t)n * D_IN * D_IN;
    // h = tanh(Xa @ W1^T), k = Xa @ W3^T  (fused via stacked [W1;W3])
    gemm128<5, 1, D_IN><<<dim3(2, 32), 256, 0, stream>>>(
        XaC[cur], D_IN, 0, W13b, D_IN,
        nullptr, 0, 0, nullptr, 0, nullptr, 0, 0, nullptr, 0,
        nullptr, hb, kb, 64, 64);
    // q = h @ W2^T
    gemm128<2, 1, D_ATTN><<<dim3(1, 32), 256, 0, stream>>>(
        hb, D_ATTN, 0, W2b, D_ATTN,
        nullptr, 0, 0, nullptr, 0, nullptr, 0, 0, nullptr, 0,
        nullptr, qb, nullptr, D_ATTN, 0);
    // S = q @ k^T
    gemm128<0, 1, D_ATTN><<<dim3(64, 32), 256, 0, stream>>>(
        qb, D_ATTN, 0, kb, D_ATTN,
        nullptr, 0, 0, nullptr, 0, nullptr, 0, 0, nullptr, 0,
        S, nullptr, nullptr, N_TOK, 0);
    // softmax + top-p -> A (bf16; block per row; bounded; idempotent)
    nucleus_block<<<N_TOK, 256, 0, stream>>>(S, Abuf, apitch);
    // Xa_new = A @ Xa : B = XaT cur; dual-write Xa_new, XaT_new
    gemm128<4, 1, N_TOK><<<dim3(8, 32), 256, 0, stream>>>(
        Abuf, apitch, 0, XaTC[cur], N_TOK,
        nullptr, 0, 0, nullptr, 0, nullptr, 0, 0, nullptr, 0,
        nullptr, XaC[nxt], XaTC[nxt], D_IN, N_TOK);
    // Z += Xf@U1^T + Xb@U2^T + Xa_new@U3^T   (fused 3-segment)
    gemm128<3, 3, D_IN><<<dim3(8, 32), 256, 0, stream>>>(
        Xbf, D_IN, -(n + 1), U1b + uoff, D_IN,
        Xbf, D_IN,  (n + 1), U2b + uoff, D_IN,
        XaC[nxt], D_IN, 0,   U3b + uoff, D_IN,
        Z, nullptr, nullptr, D_IN, 0);
  }

  // y = X + Z ; LayerNorm (in place over Z = d_out)
  ln_kernel<<<N_TOK, 256, 0, stream>>>(X, Z, gamma, beta);
}